// Round 3
// baseline (287.283 us; speedup 1.0000x reference)
//
#include <hip/hip_runtime.h>

// EdgeMLP: f = (relu(x@W1+b1)@W2+b2) for both edge sets, then masked pairwise
// cosine similarity out[i][j] = (cls1[i]==cls2[j]) * dot(f1_hat[i], f2_hat[j]).
// Stage 1: normalized features (bf16) + int labels into ws (one 64-thread block
// per 64 rows, spread over 256 blocks for latency hiding).
// Stage 2: one mfma_f32_16x16x32_bf16 per 16x16 tile with SWAPPED operands so
// each lane owns 4 consecutive output columns of one row; the block's 16x512
// fp32 tile is staged in LDS and swept out with 2KB-per-row contiguous
// nontemporal dwordx4 stores (DRAM-burst-friendly, vs 64B scattered segments).

typedef __bf16 bf16x8 __attribute__((ext_vector_type(8)));
typedef float floatx4 __attribute__((ext_vector_type(4)));

__global__ __launch_bounds__(64) void mlp_norm_kernel(
    const float* __restrict__ e1, const float* __restrict__ e2,
    const float* __restrict__ W1, const float* __restrict__ b1,
    const float* __restrict__ W2, const float* __restrict__ b2,
    __bf16* __restrict__ f1b, __bf16* __restrict__ f2b,
    int* __restrict__ cls1, int* __restrict__ cls2, int N1, int N2)
{
    __shared__ __align__(16) float sW1[192];
    __shared__ float sb1[64];
    __shared__ __align__(16) float sW2[2048];
    __shared__ float sb2[32];
    for (int i = threadIdx.x; i < 192; i += 64) sW1[i] = W1[i];
    sb1[threadIdx.x] = b1[threadIdx.x];
    for (int i = threadIdx.x; i < 2048; i += 64) sW2[i] = W2[i];
    if (threadIdx.x < 32) sb2[threadIdx.x] = b2[threadIdx.x];
    __syncthreads();

    int t = blockIdx.x * 64 + threadIdx.x;
    if (t >= N1 + N2) return;

    const float* src;
    __bf16* fout;
    int* cout;
    int row;
    if (t < N1) { row = t;      src = e1 + (size_t)row * 4; fout = f1b; cout = cls1; }
    else        { row = t - N1; src = e2 + (size_t)row * 4; fout = f2b; cout = cls2; }

    float x0 = src[0], x1 = src[1], x2 = src[2];
    int lbl = (int)src[3];

    float f[32];
#pragma unroll
    for (int k = 0; k < 32; ++k) f[k] = sb2[k];

#pragma unroll 4
    for (int j = 0; j < 64; ++j) {
        float h = fmaf(x0, sW1[j], fmaf(x1, sW1[64 + j], fmaf(x2, sW1[128 + j], sb1[j])));
        h = fmaxf(h, 0.0f);
        const floatx4* w2 = (const floatx4*)(sW2 + j * 32);
#pragma unroll
        for (int k4 = 0; k4 < 8; ++k4) {
            floatx4 w = w2[k4];
            f[k4 * 4 + 0] = fmaf(h, w[0], f[k4 * 4 + 0]);
            f[k4 * 4 + 1] = fmaf(h, w[1], f[k4 * 4 + 1]);
            f[k4 * 4 + 2] = fmaf(h, w[2], f[k4 * 4 + 2]);
            f[k4 * 4 + 3] = fmaf(h, w[3], f[k4 * 4 + 3]);
        }
    }

    float ss = 0.0f;
#pragma unroll
    for (int k = 0; k < 32; ++k) ss = fmaf(f[k], f[k], ss);
    float n = sqrtf(ss);
    float scale = (n > 1e-20f) ? (1.0f / n) : 0.0f;

    __bf16* dst = fout + (size_t)row * 32;
#pragma unroll
    for (int k = 0; k < 32; ++k) dst[k] = (__bf16)(f[k] * scale);
    cout[row] = lbl;
}

// Block = 4 waves, computes one 16-row x 512-col output region.
// MFMA operands SWAPPED vs v1: D = mfma(Afrag=f2 rows, Bfrag=f1 rows) gives
// D[m][n] = dot(f2[j + m], f1[i0 + n]) with n = lane&15 (output row offset)
// and m = (lane>>4)*4 + reg (output col offset) -> each lane holds 4
// CONSECUTIVE columns of one row: masked float4 into LDS, then block-wide
// contiguous sweep to global (2KB per row per store instruction).
#define TROW 520  // 512 + 8 floats pad: even 8-access/bank ds_write_b128
__global__ __launch_bounds__(256) void pair_cos_kernel(
    const __bf16* __restrict__ f1b, const __bf16* __restrict__ f2b,
    const int* __restrict__ cls1, const int* __restrict__ cls2,
    float* __restrict__ out, int N2, int ncg)
{
    __shared__ __align__(16) float tile[16 * TROW];  // 33280 B

    const int lane = threadIdx.x & 63;
    const int w = threadIdx.x >> 6;           // wave 0..3
    const int istrip = blockIdx.x / ncg;
    const int cg = blockIdx.x - istrip * ncg;
    const int i0 = istrip * 16;
    const int j0 = cg * 512;
    const int r16 = lane & 15;
    const int q = lane >> 4;

    // B fragment: f1 rows i0..i0+15 (n-index = lane&15), loaded once per wave.
    bf16x8 bfrag = *(const bf16x8*)(f1b + (size_t)(i0 + r16) * 32 + q * 8);
    const int c1 = cls1[i0 + r16];

#pragma unroll
    for (int t = 0; t < 8; ++t) {
        const int jc = w * 128 + t * 16;      // col offset within block tile
        const int j = j0 + jc;
        bf16x8 afrag = *(const bf16x8*)(f2b + (size_t)(j + r16) * 32 + q * 8);
        int4 c2 = *(const int4*)(cls2 + j + q * 4);

        floatx4 acc = {0.0f, 0.0f, 0.0f, 0.0f};
        floatx4 d = __builtin_amdgcn_mfma_f32_16x16x32_bf16(afrag, bfrag, acc, 0, 0, 0);

        floatx4 m;
        m[0] = (c2.x == c1) ? d[0] : 0.0f;
        m[1] = (c2.y == c1) ? d[1] : 0.0f;
        m[2] = (c2.z == c1) ? d[2] : 0.0f;
        m[3] = (c2.w == c1) ? d[3] : 0.0f;
        *(floatx4*)(tile + r16 * TROW + jc + q * 4) = m;
    }

    __syncthreads();

    // Sweep: 256 threads emit 2 rows x 2KB contiguous per iteration.
    const int r = threadIdx.x >> 7;            // 0 or 1
    const int cb = (threadIdx.x & 127) << 2;   // 0..508
    const size_t obase = (size_t)i0 * N2 + j0 + cb;
#pragma unroll
    for (int rr0 = 0; rr0 < 16; rr0 += 2) {
        const int rr = rr0 + r;
        floatx4 v = *(const floatx4*)(tile + rr * TROW + cb);
        __builtin_nontemporal_store(v, (floatx4*)(out + obase + (size_t)rr * N2));
    }
}

extern "C" void kernel_launch(void* const* d_in, const int* in_sizes, int n_in,
                              void* d_out, int out_size, void* d_ws, size_t ws_size,
                              hipStream_t stream) {
    const float* e1 = (const float*)d_in[0];
    const float* e2 = (const float*)d_in[1];
    const float* W1 = (const float*)d_in[2];
    const float* b1 = (const float*)d_in[3];
    const float* W2 = (const float*)d_in[4];
    const float* b2 = (const float*)d_in[5];
    float* out = (float*)d_out;

    const int N1 = in_sizes[0] / 4;  // 8192
    const int N2 = in_sizes[1] / 4;  // 8192

    char* ws = (char*)d_ws;
    __bf16* f1b = (__bf16*)ws;                                   // N1*32 bf16
    __bf16* f2b = (__bf16*)(ws + (size_t)N1 * 64);               // N2*32 bf16
    int* cls1 = (int*)(ws + (size_t)(N1 + N2) * 64);             // N1 ints
    int* cls2 = cls1 + N1;                                       // N2 ints

    int nrows = N1 + N2;
    mlp_norm_kernel<<<(nrows + 63) / 64, 64, 0, stream>>>(
        e1, e2, W1, b1, W2, b2, f1b, f2b, cls1, cls2, N1, N2);

    int ncg = N2 / 512;                       // 16 col-groups of 512
    int nblocks = (N1 / 16) * ncg;            // 8192 blocks, 4 waves each
    pair_cos_kernel<<<nblocks, 256, 0, stream>>>(
        f1b, f2b, cls1, cls2, out, N2, ncg);
}

// Round 4
// 277.440 us; speedup vs baseline: 1.0355x; 1.0355x over previous
//
#include <hip/hip_runtime.h>

// EdgeMLP: f = (relu(x@W1+b1)@W2+b2) for both edge sets, then masked pairwise
// cosine similarity out[i][j] = (cls1[i]==cls2[j]) * dot(f1_hat[i], f2_hat[j]).
// Stage 1: normalized features (bf16) + int labels into ws.
// Stage 2: swapped-operand mfma_f32_16x16x32_bf16 (verified passing R3) so each
// lane owns 4 consecutive output cols of one row. NEW in this version: NO
// __syncthreads — each wave stages its own 16x128 tile in private LDS
// (stride 136 dwords = conflict-free b128 floor for both write and read) and
// sweeps it out itself with 512B-per-row contiguous plain stores. 16
// independent waves/CU slip against each other, overlapping MFMA and store
// drain, which the old block-wide barrier prevented.

typedef __bf16 bf16x8 __attribute__((ext_vector_type(8)));
typedef float floatx4 __attribute__((ext_vector_type(4)));

__global__ __launch_bounds__(64) void mlp_norm_kernel(
    const float* __restrict__ e1, const float* __restrict__ e2,
    const float* __restrict__ W1, const float* __restrict__ b1,
    const float* __restrict__ W2, const float* __restrict__ b2,
    __bf16* __restrict__ f1b, __bf16* __restrict__ f2b,
    int* __restrict__ cls1, int* __restrict__ cls2, int N1, int N2)
{
    __shared__ __align__(16) float sW1[192];
    __shared__ float sb1[64];
    __shared__ __align__(16) float sW2[2048];
    __shared__ float sb2[32];
    for (int i = threadIdx.x; i < 192; i += 64) sW1[i] = W1[i];
    sb1[threadIdx.x] = b1[threadIdx.x];
    for (int i = threadIdx.x; i < 2048; i += 64) sW2[i] = W2[i];
    if (threadIdx.x < 32) sb2[threadIdx.x] = b2[threadIdx.x];
    __syncthreads();

    int t = blockIdx.x * 64 + threadIdx.x;
    if (t >= N1 + N2) return;

    const float* src;
    __bf16* fout;
    int* cout;
    int row;
    if (t < N1) { row = t;      src = e1 + (size_t)row * 4; fout = f1b; cout = cls1; }
    else        { row = t - N1; src = e2 + (size_t)row * 4; fout = f2b; cout = cls2; }

    float x0 = src[0], x1 = src[1], x2 = src[2];
    int lbl = (int)src[3];

    float f[32];
#pragma unroll
    for (int k = 0; k < 32; ++k) f[k] = sb2[k];

#pragma unroll 4
    for (int j = 0; j < 64; ++j) {
        float h = fmaf(x0, sW1[j], fmaf(x1, sW1[64 + j], fmaf(x2, sW1[128 + j], sb1[j])));
        h = fmaxf(h, 0.0f);
        const floatx4* w2 = (const floatx4*)(sW2 + j * 32);
#pragma unroll
        for (int k4 = 0; k4 < 8; ++k4) {
            floatx4 w = w2[k4];
            f[k4 * 4 + 0] = fmaf(h, w[0], f[k4 * 4 + 0]);
            f[k4 * 4 + 1] = fmaf(h, w[1], f[k4 * 4 + 1]);
            f[k4 * 4 + 2] = fmaf(h, w[2], f[k4 * 4 + 2]);
            f[k4 * 4 + 3] = fmaf(h, w[3], f[k4 * 4 + 3]);
        }
    }

    float ss = 0.0f;
#pragma unroll
    for (int k = 0; k < 32; ++k) ss = fmaf(f[k], f[k], ss);
    float n = sqrtf(ss);
    float scale = (n > 1e-20f) ? (1.0f / n) : 0.0f;

    // vectorized bf16 stores: 4 x 16B instead of 32 x 2B
    __bf16* dst = fout + (size_t)row * 32;
#pragma unroll
    for (int k8 = 0; k8 < 4; ++k8) {
        bf16x8 o;
#pragma unroll
        for (int k = 0; k < 8; ++k) o[k] = (__bf16)(f[k8 * 8 + k] * scale);
        *(bf16x8*)(dst + k8 * 8) = o;
    }
    cout[row] = lbl;
}

// Block = 4 fully independent waves; wave w owns output rows i0..i0+15,
// cols j0w..j0w+127. Swapped MFMA: D[m][n] = dot(f2[j+m], f1[i0+n]),
// n = lane&15 (out row), m = (lane>>4)*4+reg (out col) -> lane holds a
// float4 of consecutive cols. Stage in PRIVATE per-wave LDS (no barrier),
// stride 136 dwords:
//   write banks: group (2*r16 + q) & 7 -> 8 lanes/group = b128 floor
//   read  banks: rows 2it,2it+1 offset by 8 banks     -> 8 lanes/group = floor
#define SW 136
__global__ __launch_bounds__(256, 4) void pair_cos_kernel(
    const __bf16* __restrict__ f1b, const __bf16* __restrict__ f2b,
    const int* __restrict__ cls1, const int* __restrict__ cls2,
    float* __restrict__ out, int N2, int ncg)
{
    __shared__ __align__(16) float tile[4][16 * SW];  // 34816 B, 4 blocks/CU

    const int lane = threadIdx.x & 63;
    const int w = threadIdx.x >> 6;           // wave 0..3
    const int istrip = blockIdx.x / ncg;
    const int cg = blockIdx.x - istrip * ncg;
    const int i0 = istrip * 16;
    const int j0w = cg * 512 + w * 128;       // this wave's 128-col span
    const int r16 = lane & 15;
    const int q = lane >> 4;

    bf16x8 bfrag = *(const bf16x8*)(f1b + (size_t)(i0 + r16) * 32 + q * 8);
    const int c1 = cls1[i0 + r16];
    float* tw = &tile[w][0];

#pragma unroll
    for (int t = 0; t < 8; ++t) {
        const int j = j0w + t * 16;
        bf16x8 afrag = *(const bf16x8*)(f2b + (size_t)(j + r16) * 32 + q * 8);
        int4 c2 = *(const int4*)(cls2 + j + q * 4);

        floatx4 acc = {0.0f, 0.0f, 0.0f, 0.0f};
        floatx4 d = __builtin_amdgcn_mfma_f32_16x16x32_bf16(afrag, bfrag, acc, 0, 0, 0);

        floatx4 m;
        m[0] = (c2.x == c1) ? d[0] : 0.0f;
        m[1] = (c2.y == c1) ? d[1] : 0.0f;
        m[2] = (c2.z == c1) ? d[2] : 0.0f;
        m[3] = (c2.w == c1) ? d[3] : 0.0f;
        *(floatx4*)(tw + r16 * SW + t * 16 + q * 4) = m;
    }

    // same-wave LDS RAW: force the drain explicitly (no block barrier needed)
    asm volatile("s_waitcnt lgkmcnt(0)" ::: "memory");

    // Sweep: 2 rows x 512B contiguous per instruction, 8 iterations.
    const int rh = lane >> 5;                  // 0 or 1
    const int c4 = (lane & 31) << 2;           // 0..124
    const size_t obase = (size_t)i0 * N2 + j0w + c4;
#pragma unroll
    for (int it = 0; it < 8; ++it) {
        const int r = it * 2 + rh;
        floatx4 v = *(const floatx4*)(tw + r * SW + c4);
        *(floatx4*)(out + obase + (size_t)r * N2) = v;
    }
}

extern "C" void kernel_launch(void* const* d_in, const int* in_sizes, int n_in,
                              void* d_out, int out_size, void* d_ws, size_t ws_size,
                              hipStream_t stream) {
    const float* e1 = (const float*)d_in[0];
    const float* e2 = (const float*)d_in[1];
    const float* W1 = (const float*)d_in[2];
    const float* b1 = (const float*)d_in[3];
    const float* W2 = (const float*)d_in[4];
    const float* b2 = (const float*)d_in[5];
    float* out = (float*)d_out;

    const int N1 = in_sizes[0] / 4;  // 8192
    const int N2 = in_sizes[1] / 4;  // 8192

    char* ws = (char*)d_ws;
    __bf16* f1b = (__bf16*)ws;                                   // N1*32 bf16
    __bf16* f2b = (__bf16*)(ws + (size_t)N1 * 64);               // N2*32 bf16
    int* cls1 = (int*)(ws + (size_t)(N1 + N2) * 64);             // N1 ints
    int* cls2 = cls1 + N1;                                       // N2 ints

    int nrows = N1 + N2;
    mlp_norm_kernel<<<(nrows + 63) / 64, 64, 0, stream>>>(
        e1, e2, W1, b1, W2, b2, f1b, f2b, cls1, cls2, N1, N2);

    int ncg = N2 / 512;                       // 16 col-groups of 512
    int nblocks = (N1 / 16) * ncg;            // 8192 blocks, 4 indep waves each
    pair_cos_kernel<<<nblocks, 256, 0, stream>>>(
        f1b, f2b, cls1, cls2, out, N2, ncg);
}